// Round 2
// baseline (19032.953 us; speedup 1.0000x reference)
//
#include <hip/hip_runtime.h>
#include <hip/hip_bf16.h>

// CustomLSTMModel: emb(32000x300 fp32, pad_idx=0) -> LSTM(300->512, 512 steps, B=256, fp32)
//                  -> FC(512->7, fp32). tokens int32; out fp32 [256,7].
// Internal compute: bf16 MFMA (weights/x/h rounded RNE to bf16), fp32 accum, fp32 c/biases/FC.
//
// Design (unchanged from R1 except fp32 I/O + x-work hoisted above the wait):
//  - 8 batch-groups x 32 batches. 32 blocks/group; block owns 16 hidden units
//    (= 64 gate rows, unit-major: r' = unit_local*4 + gate).
//  - W_ih/W_hh MFMA A-fragments preloaded to VGPRs once (26 chunks = 104 VGPRs).
//  - Per step: [stage x_t (emb gather fp32->bf16) | S1 | 20 ih-MFMAs]  <- h-independent
//              [wait peers | fence | stage h_t | S2 | 32 hh-MFMAs | LSTM elementwise
//               (lane-local: 4 acc regs = i,f,g,o of one unit; c in VGPRs) | S3 | publish].
//  - Sync: per-block monotonic version flags, signed >= (0xAAAAAAAA poison < 1),
//    threadfence release/acquire. LDS 53.8KB + launch_bounds(256,2): all 256 blocks resident.

typedef unsigned short ushort_t;
typedef __bf16 bf16x8 __attribute__((ext_vector_type(8)));
typedef unsigned short u16x8v __attribute__((ext_vector_type(8)));
typedef float f32x4 __attribute__((ext_vector_type(4)));
typedef unsigned int u32x4 __attribute__((ext_vector_type(4)));

#define U_STRIDE 840   // ushorts: 320 (x incl zero pad) + 512 (h) + 8 pad
#define HOFF 320

__device__ __forceinline__ float sigmoidf_(float x) { return 1.0f / (1.0f + __expf(-x)); }
__device__ __forceinline__ float tanhf_(float x)    { return 1.0f - 2.0f / (__expf(2.0f * x) + 1.0f); }

__device__ __forceinline__ ushort_t f2bf(float f) {   // RNE; inputs are finite
    unsigned u = __builtin_bit_cast(unsigned, f);
    unsigned r = (u + 0x7FFFu + ((u >> 16) & 1u)) >> 16;
    return (ushort_t)r;
}
__device__ __forceinline__ float bf2f(ushort_t u) {
    unsigned v = ((unsigned)u) << 16;
    return __builtin_bit_cast(float, v);
}

__global__ __launch_bounds__(256, 2)
void lstm_fused_kernel(const int* __restrict__ tokens,    // [256][512]
                       const float* __restrict__ emb,     // [32000][300]
                       const float* __restrict__ Wih,     // [2048][300]
                       const float* __restrict__ bih,     // [2048]
                       const float* __restrict__ Whh,     // [2048][512]
                       const float* __restrict__ bhh,     // [2048]
                       const float* __restrict__ Wfc,     // [7][512]
                       const float* __restrict__ bfc,     // [7]
                       float* __restrict__ out,           // [256][7]
                       int* __restrict__ flags,           // [256]
                       ushort_t* __restrict__ hbuf)       // [2][256][512] bf16
{
    __shared__ ushort_t u_lds[32 * U_STRIDE];  // 53760 B

    const int tid = threadIdx.x;
    const int bid = blockIdx.x;
    const int g   = bid >> 5;      // batch group 0..7
    const int ib  = bid & 31;      // block-in-group -> unit slice
    const int Bg0 = g * 32;
    const int U0  = ib * 16;
    const int lane = tid & 63;
    const int wv   = tid >> 6;     // wave id 0..3 = M-tile
    const int lm   = lane & 15;
    const int q    = lane >> 4;

    // ---- preload A-fragments, fp32 -> bf16 RNE (once; latency amortized over 512 steps) ----
    bf16x8 aih[10];
    bf16x8 ahh[16];
    {
        const int rp   = 16 * wv + lm;          // row in block's 64 (unit_local*4 + gate)
        const int gi   = rp & 3;
        const int up   = rp >> 2;
        const int grow = gi * 512 + U0 + up;    // global gate row
#pragma unroll
        for (int kc = 0; kc < 10; ++kc) {
            u16x8v tmp;
#pragma unroll
            for (int j = 0; j < 8; ++j) {
                int col = 32 * kc + 8 * q + j;
                tmp[j] = (col < 300) ? f2bf(Wih[grow * 300 + col]) : (ushort_t)0;
            }
            aih[kc] = __builtin_bit_cast(bf16x8, tmp);
        }
#pragma unroll
        for (int kc = 0; kc < 16; ++kc) {
            u16x8v tmp;
#pragma unroll
            for (int j = 0; j < 8; ++j) {
                int col = 32 * kc + 8 * q + j;
                tmp[j] = f2bf(Whh[grow * 512 + col]);
            }
            ahh[kc] = __builtin_bit_cast(bf16x8, tmp);
        }
    }

    // ---- per-lane biases (fp32): unit = U0 + 4*wv + q; acc regs = gates i,f,g,o ----
    float bias0, bias1, bias2, bias3;
    {
        const int unit = U0 + 4 * wv + q;
        bias0 = bih[0 * 512 + unit] + bhh[0 * 512 + unit];
        bias1 = bih[1 * 512 + unit] + bhh[1 * 512 + unit];
        bias2 = bih[2 * 512 + unit] + bhh[2 * 512 + unit];
        bias3 = bih[3 * 512 + unit] + bhh[3 * 512 + unit];
    }

    // ---- init: zero our slice of h parity-0 (h0 = 0), publish version 1 ----
    {
        unsigned int* h32 = (unsigned int*)hbuf;          // parity 0 base
        int r = tid >> 3;                                  // 0..31 batch row
        int d = tid & 7;                                   // 0..7 dwords (16 ushorts = 16 units)
        h32[(Bg0 + r) * 256 + (U0 >> 1) + d] = 0u;
    }
    __syncthreads();
    if (tid == 0) {
        __threadfence();
        __hip_atomic_store(&flags[bid], 1, __ATOMIC_RELAXED, __HIP_MEMORY_SCOPE_AGENT);
    }

    const int myflag = g * 32 + (tid & 31);
    float cA = 0.0f, cB = 0.0f;

    for (int t = 0; t < 512; ++t) {
        // ---- stage x_t (h-independent): emb gather fp32 -> bf16 pairs ----
        {
            const int r  = tid >> 3;   // batch row 0..31
            const int ln = tid & 7;
            const int b  = Bg0 + r;
            const int token = tokens[b * 512 + t];
            const float2* s2 = (const float2*)(emb + (size_t)token * 300);
            unsigned int* dstx = (unsigned int*)(u_lds + r * U_STRIDE);
#pragma unroll 4
            for (int i = ln; i < 160; i += 8) {   // 150 bf16-pairs of x + 10 zero pads
                unsigned int v = 0u;
                if (token != 0 && i < 150) {
                    float2 p = s2[i];
                    v = (unsigned int)f2bf(p.x) | ((unsigned int)f2bf(p.y) << 16);
                }
                dstx[i] = v;
            }
        }
        __syncthreads();   // S1: x staged

        // ---- ih-MFMAs (h-independent), overlap with peers finishing step t-1 ----
        f32x4 acc0 = {0.f, 0.f, 0.f, 0.f};
        f32x4 acc1 = {0.f, 0.f, 0.f, 0.f};
        const ushort_t* u0 = u_lds + lm * U_STRIDE + 8 * q;          // nt=0 batches
        const ushort_t* u1 = u_lds + (16 + lm) * U_STRIDE + 8 * q;   // nt=1 batches
#pragma unroll
        for (int kc = 0; kc < 10; ++kc) {
            bf16x8 b0 = __builtin_bit_cast(bf16x8, *(const u16x8v*)(u0 + 32 * kc));
            bf16x8 b1 = __builtin_bit_cast(bf16x8, *(const u16x8v*)(u1 + 32 * kc));
            acc0 = __builtin_amdgcn_mfma_f32_16x16x32_bf16(aih[kc], b0, acc0, 0, 0, 0);
            acc1 = __builtin_amdgcn_mfma_f32_16x16x32_bf16(aih[kc], b1, acc1, 0, 0, 0);
        }

        // ---- wait for group peers: h[t&1] ready (monotonic versions; poison<0 safe) ----
        {
            const int target = t + 1;
            while (true) {
                int v = __hip_atomic_load(&flags[myflag], __ATOMIC_RELAXED, __HIP_MEMORY_SCOPE_AGENT);
                if (__all(v >= target)) break;
                __builtin_amdgcn_s_sleep(1);
            }
        }
        __threadfence();  // acquire: invalidate stale cached h

        // ---- stage h_t (bf16, 16B vectors) ----
        {
            const int r  = tid >> 3;
            const int ln = tid & 7;
            const int b  = Bg0 + r;
            const u32x4* h128 = (const u32x4*)(hbuf + (size_t)(t & 1) * (256 * 512) + b * 512);
            u32x4* dsth = (u32x4*)(u_lds + r * U_STRIDE + HOFF);
#pragma unroll
            for (int sg = ln; sg < 64; sg += 8)
                dsth[sg] = h128[sg];
        }
        __syncthreads();   // S2: h staged

        // ---- hh-MFMAs ----
#pragma unroll
        for (int kc = 0; kc < 16; ++kc) {
            bf16x8 b0 = __builtin_bit_cast(bf16x8, *(const u16x8v*)(u0 + HOFF + 32 * kc));
            bf16x8 b1 = __builtin_bit_cast(bf16x8, *(const u16x8v*)(u1 + HOFF + 32 * kc));
            acc0 = __builtin_amdgcn_mfma_f32_16x16x32_bf16(ahh[kc], b0, acc0, 0, 0, 0);
            acc1 = __builtin_amdgcn_mfma_f32_16x16x32_bf16(ahh[kc], b1, acc1, 0, 0, 0);
        }

        // ---- elementwise LSTM (lane-local: acc = {i,f,g,o} of one unit) + h writeback ----
        {
            ushort_t* hdst = hbuf + (size_t)((t + 1) & 1) * (256 * 512);
            const int unit = U0 + 4 * wv + q;
            {
                float ig = sigmoidf_(acc0.x + bias0);
                float fg = sigmoidf_(acc0.y + bias1);
                float gg = tanhf_(acc0.z + bias2);
                float og = sigmoidf_(acc0.w + bias3);
                cA = fg * cA + ig * gg;
                float hA = og * tanhf_(cA);
                hdst[(Bg0 + lm) * 512 + unit] = f2bf(hA);
            }
            {
                float ig = sigmoidf_(acc1.x + bias0);
                float fg = sigmoidf_(acc1.y + bias1);
                float gg = tanhf_(acc1.z + bias2);
                float og = sigmoidf_(acc1.w + bias3);
                cB = fg * cB + ig * gg;
                float hB = og * tanhf_(cB);
                hdst[(Bg0 + 16 + lm) * 512 + unit] = f2bf(hB);
            }
        }
        __syncthreads();   // S3: drains stores (compiler emits vmcnt(0) before barrier)
        if (tid == 0) {
            __threadfence();  // release: h stores agent-visible before version bump
            __hip_atomic_store(&flags[bid], t + 2, __ATOMIC_RELAXED, __HIP_MEMORY_SCOPE_AGENT);
        }
    }

    // ---- wait group done (513), then FC for batch Bg0+ib (fp32) ----
    {
        while (true) {
            int v = __hip_atomic_load(&flags[myflag], __ATOMIC_RELAXED, __HIP_MEMORY_SCOPE_AGENT);
            if (__all(v >= 513)) break;
            __builtin_amdgcn_s_sleep(1);
        }
    }
    __threadfence();

    {
        const int bb = Bg0 + ib;
        const ushort_t* hrow = hbuf + (size_t)bb * 512;   // final h in parity 0
        u16x8v hraw = *(const u16x8v*)(hrow + lane * 8);
        float hv[8];
#pragma unroll
        for (int j = 0; j < 8; ++j) hv[j] = bf2f(hraw[j]);
#pragma unroll
        for (int oo = 0; oo < 2; ++oo) {
            int o = wv + oo * 4;
            if (o < 7) {
                f32x4 w0 = *(const f32x4*)(Wfc + o * 512 + lane * 8);
                f32x4 w1 = *(const f32x4*)(Wfc + o * 512 + lane * 8 + 4);
                float s = hv[0] * w0.x + hv[1] * w0.y + hv[2] * w0.z + hv[3] * w0.w
                        + hv[4] * w1.x + hv[5] * w1.y + hv[6] * w1.z + hv[7] * w1.w;
#pragma unroll
                for (int sh = 32; sh >= 1; sh >>= 1) s += __shfl_down(s, sh);
                if (lane == 0)
                    out[bb * 7 + o] = s + bfc[o];
            }
        }
    }
}

extern "C" void kernel_launch(void* const* d_in, const int* in_sizes, int n_in,
                              void* d_out, int out_size, void* d_ws, size_t ws_size,
                              hipStream_t stream) {
    const int* tokens   = (const int*)d_in[0];
    const float* emb    = (const float*)d_in[1];
    const float* Wih    = (const float*)d_in[2];
    const float* bih    = (const float*)d_in[3];
    const float* Whh    = (const float*)d_in[4];
    const float* bhh    = (const float*)d_in[5];
    const float* Wfc    = (const float*)d_in[6];
    const float* bfc    = (const float*)d_in[7];

    int* flags     = (int*)d_ws;                       // 256 ints
    ushort_t* hbuf = (ushort_t*)((char*)d_ws + 1024);  // [2][256][512] bf16 = 512 KiB

    lstm_fused_kernel<<<dim3(256), dim3(256), 0, stream>>>(
        tokens, emb, Wih, bih, Whh, bhh, Wfc, bfc,
        (float*)d_out, flags, hbuf);
}

// Round 4
// 3120.324 us; speedup vs baseline: 6.0997x; 6.0997x over previous
//
#include <hip/hip_runtime.h>
#include <hip/hip_bf16.h>

// CustomLSTMModel: emb(32000x300 fp32, pad_idx=0) -> LSTM(300->512, 512 steps, B=256, fp32)
//                  -> FC(512->7, fp32). tokens int32; out fp32 [256,7].
// Internal: bf16 MFMA (RNE), fp32 accum/c/biases/FC. absmax vs fp32 ref ~1e-3 (R2: 9.8e-4).
//
// R4 = R3 with the h-staging bug fixed: R3 staged only 512 B of each 1024 B h row
// (k<4 over u64 covered units 0..255); units 256..511 were uninitialized LDS ->
// NaN bit patterns -> MFMA -> NaN out. Now k<8 covers all 128 u64.
//
// Design:
//  - NO __threadfence (on gfx950 agent fences emit buffer_wbl2/buffer_inv per step ->
//    L2 flush + 1.4 GB HBM refetch = R2's 19 ms). h-buffer and flags use RELAXED
//    AGENT-scope atomics (cache-bypassing, coherent at LLC, no cache maintenance);
//    emb/tokens/W stay warm in L1/L2.
//    Producer order: __syncthreads emits s_waitcnt vmcnt(0) before s_barrier.
//    Consumer order: control-dep on poll + compiler memory barrier + barrier.
//  - 8 groups x 32 batches; 16 blocks/group x 512 threads (8 waves); block owns 32 units.
//  - W fragments in VGPRs (104/lane); c in VGPRs; h double-buffered bf16 in d_ws.
//  - Only wave 0 polls (s_sleep backoff); group = bid&7 (XCD-aligned round-robin).

typedef unsigned short ushort_t;
typedef unsigned long long u64_t;
typedef __bf16 bf16x8 __attribute__((ext_vector_type(8)));
typedef unsigned short u16x8v __attribute__((ext_vector_type(8)));
typedef float f32x4 __attribute__((ext_vector_type(4)));

#define U_STRIDE 840   // ushorts: 320 (x incl zero pad) + 512 (h) + 8 pad; row = 1680B
#define HOFF 320

__device__ __forceinline__ float sigmoidf_(float x) { return 1.0f / (1.0f + __expf(-x)); }
__device__ __forceinline__ float tanhf_(float x)    { return 1.0f - 2.0f / (__expf(2.0f * x) + 1.0f); }

__device__ __forceinline__ ushort_t f2bf(float f) {   // RNE; inputs finite
    unsigned u = __builtin_bit_cast(unsigned, f);
    unsigned r = (u + 0x7FFFu + ((u >> 16) & 1u)) >> 16;
    return (ushort_t)r;
}
__device__ __forceinline__ float bf2f(ushort_t u) {
    unsigned v = ((unsigned)u) << 16;
    return __builtin_bit_cast(float, v);
}

// LLC-coherent (cache-bypassing) accessors — relaxed agent atomics, no fences.
__device__ __forceinline__ u64_t g_load64(const u64_t* p) {
    return __hip_atomic_load(p, __ATOMIC_RELAXED, __HIP_MEMORY_SCOPE_AGENT);
}
__device__ __forceinline__ void g_store64(u64_t* p, u64_t v) {
    __hip_atomic_store(p, v, __ATOMIC_RELAXED, __HIP_MEMORY_SCOPE_AGENT);
}
__device__ __forceinline__ void g_store16(ushort_t* p, ushort_t v) {
    __hip_atomic_store(p, v, __ATOMIC_RELAXED, __HIP_MEMORY_SCOPE_AGENT);
}
__device__ __forceinline__ int g_load_flag(const int* p) {
    return __hip_atomic_load(p, __ATOMIC_RELAXED, __HIP_MEMORY_SCOPE_AGENT);
}
__device__ __forceinline__ void g_store_flag(int* p, int v) {
    __hip_atomic_store(p, v, __ATOMIC_RELAXED, __HIP_MEMORY_SCOPE_AGENT);
}

__global__ __launch_bounds__(512, 2)
void lstm_fused_kernel(const int* __restrict__ tokens,    // [256][512]
                       const float* __restrict__ emb,     // [32000][300]
                       const float* __restrict__ Wih,     // [2048][300]
                       const float* __restrict__ bih,     // [2048]
                       const float* __restrict__ Whh,     // [2048][512]
                       const float* __restrict__ bhh,     // [2048]
                       const float* __restrict__ Wfc,     // [7][512]
                       const float* __restrict__ bfc,     // [7]
                       float* __restrict__ out,           // [256][7]
                       int* __restrict__ flags,           // [128]
                       ushort_t* __restrict__ hbuf)       // [2][256][512] bf16
{
    __shared__ ushort_t u_lds[32 * U_STRIDE];  // 53760 B

    const int tid = threadIdx.x;
    const int bid = blockIdx.x;
    const int g   = bid & 7;       // batch group 0..7 (XCD-aligned: round-robin dispatch)
    const int ib  = bid >> 3;      // block-in-group 0..15 -> unit slice
    const int Bg0 = g * 32;
    const int U0  = ib * 32;       // 32 units per block
    const int lane = tid & 63;
    const int wv   = tid >> 6;     // wave 0..7 = M-tile (16 gate rows each)
    const int lm   = lane & 15;
    const int q    = lane >> 4;

    // ---- preload A-fragments, fp32 -> bf16 RNE (once) ----
    bf16x8 aih[10];
    bf16x8 ahh[16];
    {
        const int rp   = 16 * wv + lm;          // row in block's 128 (unit_local*4 + gate)
        const int gi   = rp & 3;
        const int up   = rp >> 2;               // unit_local 0..31
        const int grow = gi * 512 + U0 + up;    // global gate row (i,f,g,o blocks of 512)
#pragma unroll
        for (int kc = 0; kc < 10; ++kc) {
            u16x8v tmp;
#pragma unroll
            for (int j = 0; j < 8; ++j) {
                int col = 32 * kc + 8 * q + j;
                tmp[j] = (col < 300) ? f2bf(Wih[grow * 300 + col]) : (ushort_t)0;
            }
            aih[kc] = __builtin_bit_cast(bf16x8, tmp);
        }
#pragma unroll
        for (int kc = 0; kc < 16; ++kc) {
            u16x8v tmp;
#pragma unroll
            for (int j = 0; j < 8; ++j) {
                int col = 32 * kc + 8 * q + j;
                tmp[j] = f2bf(Whh[grow * 512 + col]);
            }
            ahh[kc] = __builtin_bit_cast(bf16x8, tmp);
        }
    }

    // ---- per-lane biases (fp32): unit = U0 + 4*wv + q; acc regs = i,f,g,o ----
    float bias0, bias1, bias2, bias3;
    {
        const int unit = U0 + 4 * wv + q;
        bias0 = bih[0 * 512 + unit] + bhh[0 * 512 + unit];
        bias1 = bih[1 * 512 + unit] + bhh[1 * 512 + unit];
        bias2 = bih[2 * 512 + unit] + bhh[2 * 512 + unit];
        bias3 = bih[3 * 512 + unit] + bhh[3 * 512 + unit];
    }

    // ---- init: zero our unit-slice of h parity-0 (h0=0) via bypassing stores ----
    if (tid < 256) {
        int r = tid >> 3;        // batch row 0..31
        int d = tid & 7;         // 8 u64 = 32 units
        g_store64((u64_t*)(hbuf + (size_t)(Bg0 + r) * 512 + U0 + 4 * d), 0ull);
    }
    __syncthreads();             // drains stores before barrier
    if (tid == 0) g_store_flag(&flags[g * 16 + ib], 1);

    const int* myflag = &flags[g * 16 + (lane & 15)];
    float cA = 0.0f, cB = 0.0f;

    for (int t = 0; t < 512; ++t) {
        // ---- stage x_t (h-independent): emb gather fp32 -> bf16 pairs ----
        {
            const int r  = tid >> 4;   // batch row 0..31
            const int ln = tid & 15;
            const int b  = Bg0 + r;
            const int token = tokens[b * 512 + t];
            const float2* s2 = (const float2*)(emb + (size_t)token * 300);
            unsigned int* dstx = (unsigned int*)(u_lds + r * U_STRIDE);
#pragma unroll
            for (int k = 0; k < 10; ++k) {     // 160 dwords: 150 data + 10 zero pad
                int i = ln + 16 * k;
                unsigned int v = 0u;
                if (token != 0 && i < 150) {
                    float2 p = s2[i];
                    v = (unsigned int)f2bf(p.x) | ((unsigned int)f2bf(p.y) << 16);
                }
                dstx[i] = v;
            }
        }
        __syncthreads();   // S1: x staged

        // ---- ih-MFMAs (h-independent): overlap with peers finishing step t-1 ----
        f32x4 acc0 = {0.f, 0.f, 0.f, 0.f};
        f32x4 acc1 = {0.f, 0.f, 0.f, 0.f};
        const ushort_t* u0 = u_lds + lm * U_STRIDE + 8 * q;          // batches Bg0+0..15
        const ushort_t* u1 = u_lds + (16 + lm) * U_STRIDE + 8 * q;   // batches Bg0+16..31
#pragma unroll
        for (int kc = 0; kc < 10; ++kc) {
            bf16x8 b0 = __builtin_bit_cast(bf16x8, *(const u16x8v*)(u0 + 32 * kc));
            bf16x8 b1 = __builtin_bit_cast(bf16x8, *(const u16x8v*)(u1 + 32 * kc));
            acc0 = __builtin_amdgcn_mfma_f32_16x16x32_bf16(aih[kc], b0, acc0, 0, 0, 0);
            acc1 = __builtin_amdgcn_mfma_f32_16x16x32_bf16(aih[kc], b1, acc1, 0, 0, 0);
        }

        // ---- wave 0 polls peers' flags (monotonic; 0xAAAAAAAA poison < 1) ----
        if (wv == 0) {
            const int target = t + 1;
            while (true) {
                int v = g_load_flag(myflag);
                if (__all(v >= target)) break;
                __builtin_amdgcn_s_sleep(4);
            }
            asm volatile("" ::: "memory");   // no reordering of h loads above the poll
        }
        __syncthreads();   // S2a: release all waves

        // ---- stage h_t via bypassing u64 loads -> LDS (FULL 128 u64 = 1024 B per row) ----
        {
            const int r  = tid >> 4;
            const int ln = tid & 15;
            const u64_t* hsrc = (const u64_t*)(hbuf + (size_t)(t & 1) * (256 * 512)
                                               + (size_t)(Bg0 + r) * 512);
            u64_t* dsth = (u64_t*)(u_lds + r * U_STRIDE + HOFF);
            u64_t tmp[8];
#pragma unroll
            for (int k = 0; k < 8; ++k) tmp[k] = g_load64(hsrc + ln + 16 * k);
#pragma unroll
            for (int k = 0; k < 8; ++k) dsth[ln + 16 * k] = tmp[k];
        }
        __syncthreads();   // S2b: h staged

        // ---- hh-MFMAs ----
#pragma unroll
        for (int kc = 0; kc < 16; ++kc) {
            bf16x8 b0 = __builtin_bit_cast(bf16x8, *(const u16x8v*)(u0 + HOFF + 32 * kc));
            bf16x8 b1 = __builtin_bit_cast(bf16x8, *(const u16x8v*)(u1 + HOFF + 32 * kc));
            acc0 = __builtin_amdgcn_mfma_f32_16x16x32_bf16(ahh[kc], b0, acc0, 0, 0, 0);
            acc1 = __builtin_amdgcn_mfma_f32_16x16x32_bf16(ahh[kc], b1, acc1, 0, 0, 0);
        }

        // ---- elementwise LSTM (lane-local: acc = i,f,g,o of one unit) + h writeback ----
        {
            ushort_t* hdst = hbuf + (size_t)((t + 1) & 1) * (256 * 512);
            const int unit = U0 + 4 * wv + q;
            {
                float ig = sigmoidf_(acc0.x + bias0);
                float fg = sigmoidf_(acc0.y + bias1);
                float gg = tanhf_(acc0.z + bias2);
                float og = sigmoidf_(acc0.w + bias3);
                cA = fg * cA + ig * gg;
                g_store16(&hdst[(size_t)(Bg0 + lm) * 512 + unit], f2bf(og * tanhf_(cA)));
            }
            {
                float ig = sigmoidf_(acc1.x + bias0);
                float fg = sigmoidf_(acc1.y + bias1);
                float gg = tanhf_(acc1.z + bias2);
                float og = sigmoidf_(acc1.w + bias3);
                cB = fg * cB + ig * gg;
                g_store16(&hdst[(size_t)(Bg0 + 16 + lm) * 512 + unit], f2bf(og * tanhf_(cB)));
            }
        }
        __syncthreads();   // S3: vmcnt(0) drain -> h stores at LLC before publish
        if (tid == 0) g_store_flag(&flags[g * 16 + ib], t + 2);
    }

    // ---- wait group done (513), then FC: block handles batches Bg0+2*ib, +1 ----
    if (wv == 0) {
        while (true) {
            int v = g_load_flag(myflag);
            if (__all(v >= 513)) break;
            __builtin_amdgcn_s_sleep(4);
        }
        asm volatile("" ::: "memory");
    }
    __syncthreads();

    {
        const int bb = Bg0 + 2 * ib + (wv & 1);
        const int obase = wv >> 1;                       // 0..3
        const ushort_t* hrow = hbuf + (size_t)bb * 512;  // final h in parity 0
        u64_t h0 = g_load64((const u64_t*)(hrow + lane * 8));
        u64_t h1 = g_load64((const u64_t*)(hrow + lane * 8 + 4));
        float hv[8];
#pragma unroll
        for (int j = 0; j < 4; ++j) hv[j]     = bf2f((ushort_t)(h0 >> (16 * j)));
#pragma unroll
        for (int j = 0; j < 4; ++j) hv[4 + j] = bf2f((ushort_t)(h1 >> (16 * j)));
#pragma unroll
        for (int oo = 0; oo < 2; ++oo) {
            int o = obase + oo * 4;
            if (o < 7) {
                f32x4 w0 = *(const f32x4*)(Wfc + o * 512 + lane * 8);
                f32x4 w1 = *(const f32x4*)(Wfc + o * 512 + lane * 8 + 4);
                float s = hv[0] * w0.x + hv[1] * w0.y + hv[2] * w0.z + hv[3] * w0.w
                        + hv[4] * w1.x + hv[5] * w1.y + hv[6] * w1.z + hv[7] * w1.w;
#pragma unroll
                for (int sh = 32; sh >= 1; sh >>= 1) s += __shfl_down(s, sh);
                if (lane == 0)
                    out[bb * 7 + o] = s + bfc[o];
            }
        }
    }
}

extern "C" void kernel_launch(void* const* d_in, const int* in_sizes, int n_in,
                              void* d_out, int out_size, void* d_ws, size_t ws_size,
                              hipStream_t stream) {
    const int* tokens = (const int*)d_in[0];
    const float* emb  = (const float*)d_in[1];
    const float* Wih  = (const float*)d_in[2];
    const float* bih  = (const float*)d_in[3];
    const float* Whh  = (const float*)d_in[4];
    const float* bhh  = (const float*)d_in[5];
    const float* Wfc  = (const float*)d_in[6];
    const float* bfc  = (const float*)d_in[7];

    int* flags      = (int*)d_ws;                       // 128 ints (group g: flags[16g..16g+15])
    ushort_t* hbuf  = (ushort_t*)((char*)d_ws + 1024);  // [2][256][512] bf16 = 512 KiB

    lstm_fused_kernel<<<dim3(128), dim3(512), 0, stream>>>(
        tokens, emb, Wih, bih, Whh, bhh, Wfc, bfc,
        (float*)d_out, flags, hbuf);
}

// Round 5
// 3050.168 us; speedup vs baseline: 6.2400x; 1.0230x over previous
//
#include <hip/hip_runtime.h>
#include <hip/hip_bf16.h>

// CustomLSTMModel: emb(32000x300 fp32, pad_idx=0) -> LSTM(300->512, 512 steps, B=256, fp32)
//                  -> FC(512->7, fp32). tokens int32; out fp32 [256,7].
// Internal: bf16 MFMA (RNE), fp32 accum/c/biases/FC. absmax ~1e-3 (R2/R4: 9.8e-4).
//
// R5 changes vs R4 (3.25 ms, WRITE_SIZE 526 MB = 4x ideal):
//  - Coalesced h writeback: R4's elementwise issued 1024 scattered 2B cache-bypassing
//    stores per block per step (each a >=32B LLC sector write + drain serialization).
//    Now: elementwise -> LDS scratch [32][36] -> 256 threads x one u64 bypassing store
//    (64B-contiguous per row). 4x fewer transactions, full sectors.
//  - s_sleep(1) poll backoff (64-cyc quantum, was 256).
// Carried from R4: no fences (relaxed agent-scope atomics = LLC-coherent, no
// buffer_wbl2/inv, L1/L2 stay warm for emb/W); 8 groups x 16 blocks x 512 thr;
// W in VGPRs; c in VGPRs; wave-0-only poll; group = bid&7 (XCD round-robin).

typedef unsigned short ushort_t;
typedef unsigned long long u64_t;
typedef __bf16 bf16x8 __attribute__((ext_vector_type(8)));
typedef unsigned short u16x8v __attribute__((ext_vector_type(8)));
typedef float f32x4 __attribute__((ext_vector_type(4)));

#define U_STRIDE 840   // ushorts: 320 (x incl zero pad) + 512 (h) + 8 pad; row = 1680B
#define HOFF 320
#define SCR_S 36       // scratch row stride in ushorts (72B: 8B-aligned)

__device__ __forceinline__ float sigmoidf_(float x) { return 1.0f / (1.0f + __expf(-x)); }
__device__ __forceinline__ float tanhf_(float x)    { return 1.0f - 2.0f / (__expf(2.0f * x) + 1.0f); }

__device__ __forceinline__ ushort_t f2bf(float f) {   // RNE; inputs finite
    unsigned u = __builtin_bit_cast(unsigned, f);
    unsigned r = (u + 0x7FFFu + ((u >> 16) & 1u)) >> 16;
    return (ushort_t)r;
}
__device__ __forceinline__ float bf2f(ushort_t u) {
    unsigned v = ((unsigned)u) << 16;
    return __builtin_bit_cast(float, v);
}

// LLC-coherent (cache-bypassing) accessors — relaxed agent atomics, no fences.
__device__ __forceinline__ u64_t g_load64(const u64_t* p) {
    return __hip_atomic_load(p, __ATOMIC_RELAXED, __HIP_MEMORY_SCOPE_AGENT);
}
__device__ __forceinline__ void g_store64(u64_t* p, u64_t v) {
    __hip_atomic_store(p, v, __ATOMIC_RELAXED, __HIP_MEMORY_SCOPE_AGENT);
}
__device__ __forceinline__ int g_load_flag(const int* p) {
    return __hip_atomic_load(p, __ATOMIC_RELAXED, __HIP_MEMORY_SCOPE_AGENT);
}
__device__ __forceinline__ void g_store_flag(int* p, int v) {
    __hip_atomic_store(p, v, __ATOMIC_RELAXED, __HIP_MEMORY_SCOPE_AGENT);
}

__global__ __launch_bounds__(512, 2)
void lstm_fused_kernel(const int* __restrict__ tokens,    // [256][512]
                       const float* __restrict__ emb,     // [32000][300]
                       const float* __restrict__ Wih,     // [2048][300]
                       const float* __restrict__ bih,     // [2048]
                       const float* __restrict__ Whh,     // [2048][512]
                       const float* __restrict__ bhh,     // [2048]
                       const float* __restrict__ Wfc,     // [7][512]
                       const float* __restrict__ bfc,     // [7]
                       float* __restrict__ out,           // [256][7]
                       int* __restrict__ flags,           // [128]
                       ushort_t* __restrict__ hbuf)       // [2][256][512] bf16
{
    __shared__ ushort_t u_lds[32 * U_STRIDE];   // 53760 B
    __shared__ ushort_t h_scr[32 * SCR_S];      // 2304 B writeback bounce

    const int tid = threadIdx.x;
    const int bid = blockIdx.x;
    const int g   = bid & 7;       // batch group 0..7 (XCD-aligned: round-robin dispatch)
    const int ib  = bid >> 3;      // block-in-group 0..15 -> unit slice
    const int Bg0 = g * 32;
    const int U0  = ib * 32;       // 32 units per block
    const int lane = tid & 63;
    const int wv   = tid >> 6;     // wave 0..7 = M-tile (16 gate rows each)
    const int lm   = lane & 15;
    const int q    = lane >> 4;

    // ---- preload A-fragments, fp32 -> bf16 RNE (once) ----
    bf16x8 aih[10];
    bf16x8 ahh[16];
    {
        const int rp   = 16 * wv + lm;          // row in block's 128 (unit_local*4 + gate)
        const int gi   = rp & 3;
        const int up   = rp >> 2;               // unit_local 0..31
        const int grow = gi * 512 + U0 + up;    // global gate row (i,f,g,o blocks of 512)
#pragma unroll
        for (int kc = 0; kc < 10; ++kc) {
            u16x8v tmp;
#pragma unroll
            for (int j = 0; j < 8; ++j) {
                int col = 32 * kc + 8 * q + j;
                tmp[j] = (col < 300) ? f2bf(Wih[grow * 300 + col]) : (ushort_t)0;
            }
            aih[kc] = __builtin_bit_cast(bf16x8, tmp);
        }
#pragma unroll
        for (int kc = 0; kc < 16; ++kc) {
            u16x8v tmp;
#pragma unroll
            for (int j = 0; j < 8; ++j) {
                int col = 32 * kc + 8 * q + j;
                tmp[j] = f2bf(Whh[grow * 512 + col]);
            }
            ahh[kc] = __builtin_bit_cast(bf16x8, tmp);
        }
    }

    // ---- per-lane biases (fp32): unit = U0 + 4*wv + q; acc regs = i,f,g,o ----
    float bias0, bias1, bias2, bias3;
    {
        const int unit = U0 + 4 * wv + q;
        bias0 = bih[0 * 512 + unit] + bhh[0 * 512 + unit];
        bias1 = bih[1 * 512 + unit] + bhh[1 * 512 + unit];
        bias2 = bih[2 * 512 + unit] + bhh[2 * 512 + unit];
        bias3 = bih[3 * 512 + unit] + bhh[3 * 512 + unit];
    }

    // ---- init: zero our unit-slice of h parity-0 (h0=0) via bypassing stores ----
    if (tid < 256) {
        int r = tid >> 3;        // batch row 0..31
        int d = tid & 7;         // 8 u64 = 32 units
        g_store64((u64_t*)(hbuf + (size_t)(Bg0 + r) * 512 + U0 + 4 * d), 0ull);
    }
    __syncthreads();             // drains stores before barrier
    if (tid == 0) g_store_flag(&flags[g * 16 + ib], 1);

    const int* myflag = &flags[g * 16 + (lane & 15)];
    float cA = 0.0f, cB = 0.0f;

    for (int t = 0; t < 512; ++t) {
        // ---- stage x_t (h-independent): emb gather fp32 -> bf16 pairs ----
        {
            const int r  = tid >> 4;   // batch row 0..31
            const int ln = tid & 15;
            const int b  = Bg0 + r;
            const int token = tokens[b * 512 + t];
            const float2* s2 = (const float2*)(emb + (size_t)token * 300);
            unsigned int* dstx = (unsigned int*)(u_lds + r * U_STRIDE);
#pragma unroll
            for (int k = 0; k < 10; ++k) {     // 160 dwords: 150 data + 10 zero pad
                int i = ln + 16 * k;
                unsigned int v = 0u;
                if (token != 0 && i < 150) {
                    float2 p = s2[i];
                    v = (unsigned int)f2bf(p.x) | ((unsigned int)f2bf(p.y) << 16);
                }
                dstx[i] = v;
            }
        }
        __syncthreads();   // S1: x staged

        // ---- ih-MFMAs (h-independent): overlap with peers finishing step t-1 ----
        f32x4 acc0 = {0.f, 0.f, 0.f, 0.f};
        f32x4 acc1 = {0.f, 0.f, 0.f, 0.f};
        const ushort_t* u0 = u_lds + lm * U_STRIDE + 8 * q;          // batches Bg0+0..15
        const ushort_t* u1 = u_lds + (16 + lm) * U_STRIDE + 8 * q;   // batches Bg0+16..31
#pragma unroll
        for (int kc = 0; kc < 10; ++kc) {
            bf16x8 b0 = __builtin_bit_cast(bf16x8, *(const u16x8v*)(u0 + 32 * kc));
            bf16x8 b1 = __builtin_bit_cast(bf16x8, *(const u16x8v*)(u1 + 32 * kc));
            acc0 = __builtin_amdgcn_mfma_f32_16x16x32_bf16(aih[kc], b0, acc0, 0, 0, 0);
            acc1 = __builtin_amdgcn_mfma_f32_16x16x32_bf16(aih[kc], b1, acc1, 0, 0, 0);
        }

        // ---- wave 0 polls peers' flags (monotonic; 0xAAAAAAAA poison < 1) ----
        if (wv == 0) {
            const int target = t + 1;
            while (true) {
                int v = g_load_flag(myflag);
                if (__all(v >= target)) break;
                __builtin_amdgcn_s_sleep(1);
            }
            asm volatile("" ::: "memory");   // no reordering of h loads above the poll
        }
        __syncthreads();   // S2a: release all waves

        // ---- stage h_t via bypassing u64 loads -> LDS (128 u64 = 1024 B per row) ----
        {
            const int r  = tid >> 4;
            const int ln = tid & 15;
            const u64_t* hsrc = (const u64_t*)(hbuf + (size_t)(t & 1) * (256 * 512)
                                               + (size_t)(Bg0 + r) * 512);
            u64_t* dsth = (u64_t*)(u_lds + r * U_STRIDE + HOFF);
            u64_t tmp[8];
#pragma unroll
            for (int k = 0; k < 8; ++k) tmp[k] = g_load64(hsrc + ln + 16 * k);
#pragma unroll
            for (int k = 0; k < 8; ++k) dsth[ln + 16 * k] = tmp[k];
        }
        __syncthreads();   // S2b: h staged

        // ---- hh-MFMAs ----
#pragma unroll
        for (int kc = 0; kc < 16; ++kc) {
            bf16x8 b0 = __builtin_bit_cast(bf16x8, *(const u16x8v*)(u0 + HOFF + 32 * kc));
            bf16x8 b1 = __builtin_bit_cast(bf16x8, *(const u16x8v*)(u1 + HOFF + 32 * kc));
            acc0 = __builtin_amdgcn_mfma_f32_16x16x32_bf16(ahh[kc], b0, acc0, 0, 0, 0);
            acc1 = __builtin_amdgcn_mfma_f32_16x16x32_bf16(ahh[kc], b1, acc1, 0, 0, 0);
        }

        // ---- elementwise LSTM (lane-local: acc = i,f,g,o of one unit) -> LDS scratch ----
        {
            const int ul = 4 * wv + q;     // unit_local 0..31
            {
                float ig = sigmoidf_(acc0.x + bias0);
                float fg = sigmoidf_(acc0.y + bias1);
                float gg = tanhf_(acc0.z + bias2);
                float og = sigmoidf_(acc0.w + bias3);
                cA = fg * cA + ig * gg;
                h_scr[lm * SCR_S + ul] = f2bf(og * tanhf_(cA));
            }
            {
                float ig = sigmoidf_(acc1.x + bias0);
                float fg = sigmoidf_(acc1.y + bias1);
                float gg = tanhf_(acc1.z + bias2);
                float og = sigmoidf_(acc1.w + bias3);
                cB = fg * cB + ig * gg;
                h_scr[(16 + lm) * SCR_S + ul] = f2bf(og * tanhf_(cB));
            }
        }
        __syncthreads();   // S3a: scratch complete (lgkmcnt drain)

        // ---- coalesced bypassing writeback: 256 x u64 (64B-contiguous per row) ----
        if (tid < 256) {
            const int r = tid >> 3;    // batch row 0..31
            const int d = tid & 7;     // u64 index 0..7 (4 units each)
            u64_t v = *(const u64_t*)((const char*)h_scr + r * (SCR_S * 2) + d * 8);
            ushort_t* hdst = hbuf + (size_t)((t + 1) & 1) * (256 * 512);
            g_store64((u64_t*)(hdst + (size_t)(Bg0 + r) * 512 + U0 + 4 * d), v);
        }
        __syncthreads();   // S3b: vmcnt(0) drain -> h stores at LLC before publish
        if (tid == 0) g_store_flag(&flags[g * 16 + ib], t + 2);
    }

    // ---- wait group done (513), then FC: block handles batches Bg0+2*ib, +1 ----
    if (wv == 0) {
        while (true) {
            int v = g_load_flag(myflag);
            if (__all(v >= 513)) break;
            __builtin_amdgcn_s_sleep(1);
        }
        asm volatile("" ::: "memory");
    }
    __syncthreads();

    {
        const int bb = Bg0 + 2 * ib + (wv & 1);
        const int obase = wv >> 1;                       // 0..3
        const ushort_t* hrow = hbuf + (size_t)bb * 512;  // final h in parity 0
        u64_t h0 = g_load64((const u64_t*)(hrow + lane * 8));
        u64_t h1 = g_load64((const u64_t*)(hrow + lane * 8 + 4));
        float hv[8];
#pragma unroll
        for (int j = 0; j < 4; ++j) hv[j]     = bf2f((ushort_t)(h0 >> (16 * j)));
#pragma unroll
        for (int j = 0; j < 4; ++j) hv[4 + j] = bf2f((ushort_t)(h1 >> (16 * j)));
#pragma unroll
        for (int oo = 0; oo < 2; ++oo) {
            int o = obase + oo * 4;
            if (o < 7) {
                f32x4 w0 = *(const f32x4*)(Wfc + o * 512 + lane * 8);
                f32x4 w1 = *(const f32x4*)(Wfc + o * 512 + lane * 8 + 4);
                float s = hv[0] * w0.x + hv[1] * w0.y + hv[2] * w0.z + hv[3] * w0.w
                        + hv[4] * w1.x + hv[5] * w1.y + hv[6] * w1.z + hv[7] * w1.w;
#pragma unroll
                for (int sh = 32; sh >= 1; sh >>= 1) s += __shfl_down(s, sh);
                if (lane == 0)
                    out[bb * 7 + o] = s + bfc[o];
            }
        }
    }
}

extern "C" void kernel_launch(void* const* d_in, const int* in_sizes, int n_in,
                              void* d_out, int out_size, void* d_ws, size_t ws_size,
                              hipStream_t stream) {
    const int* tokens = (const int*)d_in[0];
    const float* emb  = (const float*)d_in[1];
    const float* Wih  = (const float*)d_in[2];
    const float* bih  = (const float*)d_in[3];
    const float* Whh  = (const float*)d_in[4];
    const float* bhh  = (const float*)d_in[5];
    const float* Wfc  = (const float*)d_in[6];
    const float* bfc  = (const float*)d_in[7];

    int* flags      = (int*)d_ws;                       // 128 ints (group g: flags[16g..16g+15])
    ushort_t* hbuf  = (ushort_t*)((char*)d_ws + 1024);  // [2][256][512] bf16 = 512 KiB

    lstm_fused_kernel<<<dim3(128), dim3(512), 0, stream>>>(
        tokens, emb, Wih, bih, Whh, bhh, Wfc, bfc,
        (float*)d_out, flags, hbuf);
}

// Round 6
// 2136.648 us; speedup vs baseline: 8.9079x; 1.4275x over previous
//
#include <hip/hip_runtime.h>
#include <hip/hip_bf16.h>

// CustomLSTMModel: emb(32000x300 fp32, pad_idx=0) -> LSTM(300->512, 512 steps, B=256, fp32)
//                  -> FC(512->7, fp32). tokens int32; out fp32 [256,7].
// Internal: bf16 MFMA (RNE), fp32 accum/c/biases/FC. absmax ~1e-3 (R2/R4/R5: 9.8e-4).
//
// R6 changes vs R5 (3.20 ms; FETCH 168 MB = emb gather ~0% LLC reuse, HBM latency
// at the top of every step on the serial critical path + jitter into the group sync):
//  - Software prefetch: x_{t+1} emb rows loaded into 20 VGPRs at the TOP of step t,
//    consumed (fp32->bf16, ->LDS) at the top of step t+1. HBM latency (~900cyc) now
//    overlaps the whole step body instead of serializing before S1. Token for t+2
//    prefetched the same way (row-major tokens line stays in L1).
// Carried from R5/R4: no fences (relaxed agent-scope atomics, LLC-coherent, no
// buffer_wbl2/inv); coalesced u64 h writeback via LDS bounce; 8 groups x 16 blocks
// x 512 thr; W in VGPRs; c in VGPRs; wave-0-only poll; group = bid&7.

typedef unsigned short ushort_t;
typedef unsigned long long u64_t;
typedef __bf16 bf16x8 __attribute__((ext_vector_type(8)));
typedef unsigned short u16x8v __attribute__((ext_vector_type(8)));
typedef float f32x4 __attribute__((ext_vector_type(4)));

#define U_STRIDE 840   // ushorts: 320 (x incl zero pad) + 512 (h) + 8 pad; row = 1680B
#define HOFF 320
#define SCR_S 36       // scratch row stride in ushorts (72B)

__device__ __forceinline__ float sigmoidf_(float x) { return 1.0f / (1.0f + __expf(-x)); }
__device__ __forceinline__ float tanhf_(float x)    { return 1.0f - 2.0f / (__expf(2.0f * x) + 1.0f); }

__device__ __forceinline__ ushort_t f2bf(float f) {   // RNE; inputs finite
    unsigned u = __builtin_bit_cast(unsigned, f);
    unsigned r = (u + 0x7FFFu + ((u >> 16) & 1u)) >> 16;
    return (ushort_t)r;
}
__device__ __forceinline__ float bf2f(ushort_t u) {
    unsigned v = ((unsigned)u) << 16;
    return __builtin_bit_cast(float, v);
}

// LLC-coherent (cache-bypassing) accessors — relaxed agent atomics, no fences.
__device__ __forceinline__ u64_t g_load64(const u64_t* p) {
    return __hip_atomic_load(p, __ATOMIC_RELAXED, __HIP_MEMORY_SCOPE_AGENT);
}
__device__ __forceinline__ void g_store64(u64_t* p, u64_t v) {
    __hip_atomic_store(p, v, __ATOMIC_RELAXED, __HIP_MEMORY_SCOPE_AGENT);
}
__device__ __forceinline__ int g_load_flag(const int* p) {
    return __hip_atomic_load(p, __ATOMIC_RELAXED, __HIP_MEMORY_SCOPE_AGENT);
}
__device__ __forceinline__ void g_store_flag(int* p, int v) {
    __hip_atomic_store(p, v, __ATOMIC_RELAXED, __HIP_MEMORY_SCOPE_AGENT);
}

__global__ __launch_bounds__(512, 2)
void lstm_fused_kernel(const int* __restrict__ tokens,    // [256][512]
                       const float* __restrict__ emb,     // [32000][300]
                       const float* __restrict__ Wih,     // [2048][300]
                       const float* __restrict__ bih,     // [2048]
                       const float* __restrict__ Whh,     // [2048][512]
                       const float* __restrict__ bhh,     // [2048]
                       const float* __restrict__ Wfc,     // [7][512]
                       const float* __restrict__ bfc,     // [7]
                       float* __restrict__ out,           // [256][7]
                       int* __restrict__ flags,           // [128]
                       ushort_t* __restrict__ hbuf)       // [2][256][512] bf16
{
    __shared__ ushort_t u_lds[32 * U_STRIDE];   // 53760 B
    __shared__ ushort_t h_scr[32 * SCR_S];      // 2304 B writeback bounce

    const int tid = threadIdx.x;
    const int bid = blockIdx.x;
    const int g   = bid & 7;       // batch group 0..7 (XCD-aligned: round-robin dispatch)
    const int ib  = bid >> 3;      // block-in-group 0..15 -> unit slice
    const int Bg0 = g * 32;
    const int U0  = ib * 32;       // 32 units per block
    const int lane = tid & 63;
    const int wv   = tid >> 6;     // wave 0..7 = M-tile (16 gate rows each)
    const int lm   = lane & 15;
    const int q    = lane >> 4;

    // ---- preload A-fragments, fp32 -> bf16 RNE (once) ----
    bf16x8 aih[10];
    bf16x8 ahh[16];
    {
        const int rp   = 16 * wv + lm;          // row in block's 128 (unit_local*4 + gate)
        const int gi   = rp & 3;
        const int up   = rp >> 2;               // unit_local 0..31
        const int grow = gi * 512 + U0 + up;    // global gate row (i,f,g,o blocks of 512)
#pragma unroll
        for (int kc = 0; kc < 10; ++kc) {
            u16x8v tmp;
#pragma unroll
            for (int j = 0; j < 8; ++j) {
                int col = 32 * kc + 8 * q + j;
                tmp[j] = (col < 300) ? f2bf(Wih[grow * 300 + col]) : (ushort_t)0;
            }
            aih[kc] = __builtin_bit_cast(bf16x8, tmp);
        }
#pragma unroll
        for (int kc = 0; kc < 16; ++kc) {
            u16x8v tmp;
#pragma unroll
            for (int j = 0; j < 8; ++j) {
                int col = 32 * kc + 8 * q + j;
                tmp[j] = f2bf(Whh[grow * 512 + col]);
            }
            ahh[kc] = __builtin_bit_cast(bf16x8, tmp);
        }
    }

    // ---- per-lane biases (fp32): unit = U0 + 4*wv + q; acc regs = i,f,g,o ----
    float bias0, bias1, bias2, bias3;
    {
        const int unit = U0 + 4 * wv + q;
        bias0 = bih[0 * 512 + unit] + bhh[0 * 512 + unit];
        bias1 = bih[1 * 512 + unit] + bhh[1 * 512 + unit];
        bias2 = bih[2 * 512 + unit] + bhh[2 * 512 + unit];
        bias3 = bih[3 * 512 + unit] + bhh[3 * 512 + unit];
    }

    // ---- init: zero our unit-slice of h parity-0 (h0=0) via bypassing stores ----
    if (tid < 256) {
        int r = tid >> 3;        // batch row 0..31
        int d = tid & 7;         // 8 u64 = 32 units
        g_store64((u64_t*)(hbuf + (size_t)(Bg0 + r) * 512 + U0 + 4 * d), 0ull);
    }
    __syncthreads();             // drains stores before barrier
    if (tid == 0) g_store_flag(&flags[g * 16 + ib], 1);

    const int* myflag = &flags[g * 16 + (lane & 15)];
    float cA = 0.0f, cB = 0.0f;

    // ---- x prefetch state: thread handles row xr = tid>>4, elements ln+16k ----
    const int xr  = tid >> 4;        // batch row 0..31
    const int xln = tid & 15;
    const int xb  = Bg0 + xr;
    int tok_cur = tokens[xb * 512 + 0];
    int tok_nxt = tokens[xb * 512 + 1];
    float2 xp[10];
    {
        const float2* s2 = (const float2*)(emb + (size_t)tok_cur * 300);
#pragma unroll
        for (int k = 0; k < 10; ++k) {
            int i = xln + 16 * k;
            if (i < 150) xp[k] = s2[i];
        }
    }

    for (int t = 0; t < 512; ++t) {
        // ---- consume prefetched x_t: fp32 -> bf16 pairs -> LDS ----
        {
            unsigned int* dstx = (unsigned int*)(u_lds + xr * U_STRIDE);
            const bool tz = (tok_cur != 0);
#pragma unroll
            for (int k = 0; k < 10; ++k) {     // 160 dwords: 150 data + 10 zero pad
                int i = xln + 16 * k;
                unsigned int v = 0u;
                if (tz && i < 150)
                    v = (unsigned int)f2bf(xp[k].x) | ((unsigned int)f2bf(xp[k].y) << 16);
                dstx[i] = v;
            }
        }
        // ---- issue prefetch for x_{t+1} (overlaps the whole step body) ----
        {
            tok_cur = tok_nxt;
            const float2* s2 = (const float2*)(emb + (size_t)tok_cur * 300);
#pragma unroll
            for (int k = 0; k < 10; ++k) {
                int i = xln + 16 * k;
                if (i < 150) xp[k] = s2[i];
            }
            int t2 = (t + 2 < 512) ? (t + 2) : 511;
            tok_nxt = tokens[xb * 512 + t2];
        }
        __syncthreads();   // S1: x staged

        // ---- ih-MFMAs (h-independent) ----
        f32x4 acc0 = {0.f, 0.f, 0.f, 0.f};
        f32x4 acc1 = {0.f, 0.f, 0.f, 0.f};
        const ushort_t* u0 = u_lds + lm * U_STRIDE + 8 * q;          // batches Bg0+0..15
        const ushort_t* u1 = u_lds + (16 + lm) * U_STRIDE + 8 * q;   // batches Bg0+16..31
#pragma unroll
        for (int kc = 0; kc < 10; ++kc) {
            bf16x8 b0 = __builtin_bit_cast(bf16x8, *(const u16x8v*)(u0 + 32 * kc));
            bf16x8 b1 = __builtin_bit_cast(bf16x8, *(const u16x8v*)(u1 + 32 * kc));
            acc0 = __builtin_amdgcn_mfma_f32_16x16x32_bf16(aih[kc], b0, acc0, 0, 0, 0);
            acc1 = __builtin_amdgcn_mfma_f32_16x16x32_bf16(aih[kc], b1, acc1, 0, 0, 0);
        }

        // ---- wave 0 polls peers' flags (monotonic; 0xAAAAAAAA poison < 1) ----
        if (wv == 0) {
            const int target = t + 1;
            while (true) {
                int v = g_load_flag(myflag);
                if (__all(v >= target)) break;
                __builtin_amdgcn_s_sleep(1);
            }
            asm volatile("" ::: "memory");   // no reordering of h loads above the poll
        }
        __syncthreads();   // S2a: release all waves

        // ---- stage h_t via bypassing u64 loads -> LDS (128 u64 = 1024 B per row) ----
        {
            const int r  = tid >> 4;
            const int ln = tid & 15;
            const u64_t* hsrc = (const u64_t*)(hbuf + (size_t)(t & 1) * (256 * 512)
                                               + (size_t)(Bg0 + r) * 512);
            u64_t* dsth = (u64_t*)(u_lds + r * U_STRIDE + HOFF);
            u64_t tmp[8];
#pragma unroll
            for (int k = 0; k < 8; ++k) tmp[k] = g_load64(hsrc + ln + 16 * k);
#pragma unroll
            for (int k = 0; k < 8; ++k) dsth[ln + 16 * k] = tmp[k];
        }
        __syncthreads();   // S2b: h staged

        // ---- hh-MFMAs ----
#pragma unroll
        for (int kc = 0; kc < 16; ++kc) {
            bf16x8 b0 = __builtin_bit_cast(bf16x8, *(const u16x8v*)(u0 + HOFF + 32 * kc));
            bf16x8 b1 = __builtin_bit_cast(bf16x8, *(const u16x8v*)(u1 + HOFF + 32 * kc));
            acc0 = __builtin_amdgcn_mfma_f32_16x16x32_bf16(ahh[kc], b0, acc0, 0, 0, 0);
            acc1 = __builtin_amdgcn_mfma_f32_16x16x32_bf16(ahh[kc], b1, acc1, 0, 0, 0);
        }

        // ---- elementwise LSTM (lane-local: acc = i,f,g,o of one unit) -> LDS scratch ----
        {
            const int ul = 4 * wv + q;     // unit_local 0..31
            {
                float ig = sigmoidf_(acc0.x + bias0);
                float fg = sigmoidf_(acc0.y + bias1);
                float gg = tanhf_(acc0.z + bias2);
                float og = sigmoidf_(acc0.w + bias3);
                cA = fg * cA + ig * gg;
                h_scr[lm * SCR_S + ul] = f2bf(og * tanhf_(cA));
            }
            {
                float ig = sigmoidf_(acc1.x + bias0);
                float fg = sigmoidf_(acc1.y + bias1);
                float gg = tanhf_(acc1.z + bias2);
                float og = sigmoidf_(acc1.w + bias3);
                cB = fg * cB + ig * gg;
                h_scr[(16 + lm) * SCR_S + ul] = f2bf(og * tanhf_(cB));
            }
        }
        __syncthreads();   // S3a: scratch complete (lgkmcnt drain)

        // ---- coalesced bypassing writeback: 256 x u64 (64B-contiguous per row) ----
        if (tid < 256) {
            const int r = tid >> 3;    // batch row 0..31
            const int d = tid & 7;     // u64 index 0..7 (4 units each)
            u64_t v = *(const u64_t*)((const char*)h_scr + r * (SCR_S * 2) + d * 8);
            ushort_t* hdst = hbuf + (size_t)((t + 1) & 1) * (256 * 512);
            g_store64((u64_t*)(hdst + (size_t)(Bg0 + r) * 512 + U0 + 4 * d), v);
        }
        __syncthreads();   // S3b: vmcnt(0) drain -> h stores at LLC before publish
        if (tid == 0) g_store_flag(&flags[g * 16 + ib], t + 2);
    }

    // ---- wait group done (513), then FC: block handles batches Bg0+2*ib, +1 ----
    if (wv == 0) {
        while (true) {
            int v = g_load_flag(myflag);
            if (__all(v >= 513)) break;
            __builtin_amdgcn_s_sleep(1);
        }
        asm volatile("" ::: "memory");
    }
    __syncthreads();

    {
        const int bb = Bg0 + 2 * ib + (wv & 1);
        const int obase = wv >> 1;                       // 0..3
        const ushort_t* hrow = hbuf + (size_t)bb * 512;  // final h in parity 0
        u64_t h0 = g_load64((const u64_t*)(hrow + lane * 8));
        u64_t h1 = g_load64((const u64_t*)(hrow + lane * 8 + 4));
        float hv[8];
#pragma unroll
        for (int j = 0; j < 4; ++j) hv[j]     = bf2f((ushort_t)(h0 >> (16 * j)));
#pragma unroll
        for (int j = 0; j < 4; ++j) hv[4 + j] = bf2f((ushort_t)(h1 >> (16 * j)));
#pragma unroll
        for (int oo = 0; oo < 2; ++oo) {
            int o = obase + oo * 4;
            if (o < 7) {
                f32x4 w0 = *(const f32x4*)(Wfc + o * 512 + lane * 8);
                f32x4 w1 = *(const f32x4*)(Wfc + o * 512 + lane * 8 + 4);
                float s = hv[0] * w0.x + hv[1] * w0.y + hv[2] * w0.z + hv[3] * w0.w
                        + hv[4] * w1.x + hv[5] * w1.y + hv[6] * w1.z + hv[7] * w1.w;
#pragma unroll
                for (int sh = 32; sh >= 1; sh >>= 1) s += __shfl_down(s, sh);
                if (lane == 0)
                    out[bb * 7 + o] = s + bfc[o];
            }
        }
    }
}

extern "C" void kernel_launch(void* const* d_in, const int* in_sizes, int n_in,
                              void* d_out, int out_size, void* d_ws, size_t ws_size,
                              hipStream_t stream) {
    const int* tokens = (const int*)d_in[0];
    const float* emb  = (const float*)d_in[1];
    const float* Wih  = (const float*)d_in[2];
    const float* bih  = (const float*)d_in[3];
    const float* Whh  = (const float*)d_in[4];
    const float* bhh  = (const float*)d_in[5];
    const float* Wfc  = (const float*)d_in[6];
    const float* bfc  = (const float*)d_in[7];

    int* flags      = (int*)d_ws;                       // 128 ints (group g: flags[16g..16g+15])
    ushort_t* hbuf  = (ushort_t*)((char*)d_ws + 1024);  // [2][256][512] bf16 = 512 KiB

    lstm_fused_kernel<<<dim3(128), dim3(512), 0, stream>>>(
        tokens, emb, Wih, bih, Whh, bhh, Wfc, bfc,
        (float*)d_out, flags, hbuf);
}